// Round 22
// baseline (250.051 us; speedup 1.0000x reference)
//
#include <hip/hip_runtime.h>
#include <stdint.h>
#include <stddef.h>

typedef __attribute__((ext_vector_type(8))) short bf16x8;
typedef __attribute__((ext_vector_type(4))) float f32x4;
typedef __attribute__((ext_vector_type(4))) int i32x4;

#define NH 128
#define NW 128
#define NC 64
#define NF 256
#define SLOT 16384                 // one x-row tile in LDS: [w=128][cb=8 x 16B], XOR-swizzled
#define EBS 136                    // epi row stride (floats): 544B, 16B-aligned rows

__device__ __forceinline__ unsigned short f2b(float f) {
  union { float f; uint32_t u; } t; t.f = f;
  uint32_t u = t.u;
  return (unsigned short)((u + 0x7fffu + ((u >> 16) & 1u)) >> 16);
}

// raw barrier: orders LDS ops across waves WITHOUT draining vmcnt — in-flight
// NT stores keep flying. Correctness-verified R11/R12/R20/R21.
#define EPI_BAR() do { \
  asm volatile("s_waitcnt lgkmcnt(0)" ::: "memory"); \
  __builtin_amdgcn_sched_barrier(0); \
  __builtin_amdgcn_s_barrier(); \
  __builtin_amdgcn_sched_barrier(0); } while (0)

// prep: B table only (72 blocks, ~3 us). Per-wave fragment order (R8-verified):
//   u16 elem ((fi*9+s)*16 + cf*2 + kk)*512 + lane*8 + e
//     = kern[(s*64 + (kk*4+(lane>>4))*8 + e)*NF + fi*128 + cf*16 + (lane&15)]
__global__ void prep_bt(const float* __restrict__ kr, unsigned short* __restrict__ ws) {
  int t = blockIdx.x * 256 + threadIdx.x;   // [0, 18432)
  int lane = t & 63;
  int kk   = (t >> 6) & 1;
  int cf   = (t >> 7) & 7;
  int rest = t >> 10;          // fi*9 + s
  int s  = rest % 9;
  int fi = rest / 9;
  int l15 = lane & 15, l4 = lane >> 4;
  int col = fi * 128 + cf * 16 + l15;
  int k0  = s * 64 + (kk * 4 + l4) * 8;
  unsigned short* dst = ws + (size_t)t * 8;
  const float* src = kr + (size_t)k0 * NF + col;
  #pragma unroll
  for (int e = 0; e < 8; ++e) dst[e] = f2b(src[(size_t)e * NF]);
}

// conv: R21 body (2-row M-tile, dbuf B, swapped MFMA, b128 deposit, NT
// full-line stores) processed TWICE per block (grid 1024): tile 0's NT
// store burst drains under tile 1's staging + compute (EPI_BAR-only
// inter-tile sync), instead of at s_endpgm while holding wave slots.
__global__ __launch_bounds__(256, 2)
void conv_main(const float* __restrict__ x, const unsigned short* __restrict__ bt,
               const float* __restrict__ bias, float* __restrict__ out)
{
  __shared__ __align__(16) char lds[4 * SLOT];   // 64 KB (A staging; epi reuses)

  const int tid  = threadIdx.x;
  const int lane = tid & 63;
  const int l15  = lane & 15;
  const int l4   = lane >> 4;
  const int wid  = tid >> 6;
  const int wm   = wid >> 1;    // 2: w-half
  const int wn   = wid & 1;     // 2: F-half of this fi half (64 cols)

  // XCD-aware bijective swizzle: nwg=1024, 128 per XCD.
  int bid  = (int)blockIdx.x;
  int work = (bid & 7) * 128 + (bid >> 3);
  int fi  = work & 1;
  int rest = work >> 1;         // 0..511 : (b, h-quad)
  int bb  = rest >> 5;
  int h0  = (rest & 31) * 4;    // 4 rows per block = 2 tiles of 2
  int F0  = fi * 128;

  const char* bimg = (const char*)bt + (size_t)fi * 9 * 16384;
  const int boff = (wn * 4) * 2048 + lane * 16;

  // compressed A-address LUT (R10-verified), shared by all tiles/rows:
  int trow[3], swz[3];
  #pragma unroll
  for (int dwi = 0; dwi < 3; ++dwi) {
    int t = l15 + 1 - dwi;
    trow[dwi] = ((wm * 64 + t) & 127) * 128;
    swz[dwi]  = (l4 ^ (t & 7)) << 4;
  }

  f32x4 bq[4];
  #pragma unroll
  for (int n = 0; n < 4; ++n)
    bq[n] = *(const f32x4*)(bias + F0 + wn * 64 + n * 16 + l4 * 4);

  bf16x8 breg[2][4][2];   // double buffer = 64 VGPR, all-static indices

  // ---- B(0) -> buf0 for tile 0 (issues first, flies under staging) ----
  #pragma unroll
  for (int n = 0; n < 4; ++n)
    #pragma unroll
    for (int kk = 0; kk < 2; ++kk)
      breg[0][n][kk] = *(const bf16x8*)(bimg + boff + n * 2048 + kk * 1024);

  #pragma unroll 1
  for (int tile = 0; tile < 2; ++tile) {
    const int hb = h0 + tile * 2;       // first output row of this tile

    // ---- stage A rows hb-1..hb+2 -> slots 0..3 (cast in-kernel) ----
    #pragma unroll
    for (int i = 0; i < 16; ++i) {
      int idx = tid + i * 256;          // 4096 16B-blocks (4 rows)
      int cb = idx & 7;
      int w  = (idx >> 3) & 127;
      int r  = idx >> 10;               // 0..3
      int xr = (hb + r + 127) & 127;    // row hb-1+r
      const float* src = x + (((size_t)(bb * NH + xr) * NW + w) * NC + cb * 8);
      float4 a0 = *(const float4*)(src);
      float4 a1 = *(const float4*)(src + 4);
      union { unsigned short u[8]; i32x4 v; } p;
      p.u[0] = f2b(a0.x); p.u[1] = f2b(a0.y); p.u[2] = f2b(a0.z); p.u[3] = f2b(a0.w);
      p.u[4] = f2b(a1.x); p.u[5] = f2b(a1.y); p.u[6] = f2b(a1.z); p.u[7] = f2b(a1.w);
      *(i32x4*)(lds + (r * SLOT + w * 128 + ((cb ^ (w & 7)) << 4))) = p.v;
    }
    // staged ds_writes visible to all waves; tile-0 NT stores keep flying
    EPI_BAR();

    f32x4 acc[2][4][4];   // [row][m][n], swapped layout — 128 VGPR
    #pragma unroll
    for (int rr = 0; rr < 2; ++rr)
      #pragma unroll
      for (int m = 0; m < 4; ++m)
        #pragma unroll
        for (int n = 0; n < 4; ++n)
          acc[rr][m][n] = (f32x4){0.f, 0.f, 0.f, 0.f};

    #pragma unroll
    for (int s = 0; s < 9; ++s) {
      if (s < 8) {  // depth-1 B prefetch -> other buffer
        const char* bs = bimg + (size_t)(s + 1) * 16384 + boff;
        #pragma unroll
        for (int n = 0; n < 4; ++n)
          #pragma unroll
          for (int kk = 0; kk < 2; ++kk)
            breg[(s + 1) & 1][n][kk] = *(const bf16x8*)(bs + n * 2048 + kk * 1024);
      }
      const int dwi = s / 3;                        // static
      #pragma unroll
      for (int kk = 0; kk < 2; ++kk) {
        #pragma unroll
        for (int rr = 0; rr < 2; ++rr) {
          const int slotb = (rr + 2 - (s % 3)) * SLOT;   // static, 0..3
          bf16x8 af[4];
          #pragma unroll
          for (int m = 0; m < 4; ++m) {
            int addr = slotb + ((trow[dwi] + m * 2048) & 16383) + swz[dwi];
            af[m] = *(const bf16x8*)(lds + (addr ^ (kk << 6)));
          }
          __builtin_amdgcn_s_setprio(1);
          #pragma unroll
          for (int m = 0; m < 4; ++m)
            #pragma unroll
            for (int n = 0; n < 4; ++n)
              acc[rr][m][n] = __builtin_amdgcn_mfma_f32_16x16x32_bf16(
                  breg[s & 1][n][kk], af[m], acc[rr][m][n], 0, 0, 0);   // SWAPPED
          __builtin_amdgcn_s_setprio(0);
        }
      }
    }

    if (tile == 0) {   // issue next tile's B(0)->buf0 now: flies under epi
      #pragma unroll
      for (int n = 0; n < 4; ++n)
        #pragma unroll
        for (int kk = 0; kk < 2; ++kk)
          breg[0][n][kk] = *(const bf16x8*)(bimg + boff + n * 2048 + kk * 1024);
    }

    // ---- epilogue: b128 deposit + NT full-line stores, raw barriers ----
    EPI_BAR();                          // A ds_reads complete before eb overwrite
    float* eb = (float*)lds;            // [64][EBS=136] f32 tile (34.8 KB)

    #pragma unroll
    for (int rr = 0; rr < 2; ++rr) {
      #pragma unroll
      for (int chunk = 0; chunk < 2; ++chunk) {
        if (wm == chunk) {              // owning wave-pair deposits acc+bias
          #pragma unroll
          for (int m = 0; m < 4; ++m) {
            int r = m * 16 + l15;       // 0..63 chunk-local w row
            #pragma unroll
            for (int n = 0; n < 4; ++n) {
              int c = wn * 64 + n * 16 + l4 * 4;
              *(f32x4*)(eb + r * EBS + c) = acc[rr][m][n] + bq[n];
            }
          }
        }
        EPI_BAR();                      // deposits visible (lgkmcnt only)
        size_t obase = ((size_t)(bb * NH + hb + rr) * NW + chunk * 64) * NF + F0;
        #pragma unroll
        for (int i = 0; i < 8; ++i) {
          int r = i * 8 + wid * 2 + (lane >> 5);
          int c = (lane & 31) * 4;
          f32x4 v = *(const f32x4*)(eb + r * EBS + c);
          __builtin_nontemporal_store(v, (f32x4*)(out + obase + (size_t)r * NF + c));
        }
        if (rr != 1 || chunk != 1) EPI_BAR();   // eb reads done; stores fly on
      }
    }
    // tile 1's staging may overwrite eb/slots only after all eb reads done:
    if (tile == 0) EPI_BAR();
  }
}

extern "C" void kernel_launch(void* const* d_in, const int* in_sizes, int n_in,
                              void* d_out, int out_size, void* d_ws, size_t ws_size,
                              hipStream_t stream) {
  const float* x    = (const float*)d_in[0];
  const float* kern = (const float*)d_in[1];
  const float* bias = (const float*)d_in[2];
  float* out = (float*)d_out;
  unsigned short* bt = (unsigned short*)d_ws;   // 294912 bytes

  prep_bt<<<dim3(72), dim3(256), 0, stream>>>(kern, bt);
  conv_main<<<dim3(1024), dim3(256), 0, stream>>>(x, bt, bias, out);
}

// Round 23
// 91.904 us; speedup vs baseline: 2.7208x; 2.7208x over previous
//
#include <hip/hip_runtime.h>
#include <stdint.h>
#include <stddef.h>

typedef __attribute__((ext_vector_type(8))) short bf16x8;
typedef __attribute__((ext_vector_type(4))) float f32x4;
typedef __attribute__((ext_vector_type(4))) int i32x4;

#define NH 128
#define NW 128
#define NC 64
#define NF 256
#define SLOT 16384                 // one x-row tile in LDS: [w=128][cb=8 x 16B], XOR-swizzled
#define EBS 136                    // epi row stride (floats): 544B, 16B-aligned rows

__device__ __forceinline__ unsigned short f2b(float f) {
  union { float f; uint32_t u; } t; t.f = f;
  uint32_t u = t.u;
  return (unsigned short)((u + 0x7fffu + ((u >> 16) & 1u)) >> 16);
}

// raw barrier: orders LDS ops across waves WITHOUT draining vmcnt — in-flight
// NT stores keep flying. Correctness-verified R11/R12/R20/R21.
#define EPI_BAR() do { \
  asm volatile("s_waitcnt lgkmcnt(0)" ::: "memory"); \
  __builtin_amdgcn_sched_barrier(0); \
  __builtin_amdgcn_s_barrier(); \
  __builtin_amdgcn_sched_barrier(0); } while (0)

// prep: B table only (72 blocks, ~3 us). Per-wave fragment order (R8-verified):
//   u16 elem ((fi*9+s)*16 + cf*2 + kk)*512 + lane*8 + e
//     = kern[(s*64 + (kk*4+(lane>>4))*8 + e)*NF + fi*128 + cf*16 + (lane&15)]
__global__ void prep_bt(const float* __restrict__ kr, unsigned short* __restrict__ ws) {
  int t = blockIdx.x * 256 + threadIdx.x;   // [0, 18432)
  int lane = t & 63;
  int kk   = (t >> 6) & 1;
  int cf   = (t >> 7) & 7;
  int rest = t >> 10;          // fi*9 + s
  int s  = rest % 9;
  int fi = rest / 9;
  int l15 = lane & 15, l4 = lane >> 4;
  int col = fi * 128 + cf * 16 + l15;
  int k0  = s * 64 + (kk * 4 + l4) * 8;
  unsigned short* dst = ws + (size_t)t * 8;
  const float* src = kr + (size_t)k0 * NF + col;
  #pragma unroll
  for (int e = 0; e < 8; ++e) dst[e] = f2b(src[(size_t)e * NF]);
}

// conv (R21, best verified: 91.9 us): M-TILE = 2 h-rows per block (grid 2048).
// Both rows' MFMAs consume the SAME breg inside each shift -> B L2 traffic
// halves, staging per output halves, x L2 re-reads halve. 4-slot LDS
// (rows h0-1..h0+2, 64 KB), acc[2][4][4] = 128 VGPR, fully unrolled body
// (no outer loop -> no R22-style spill), launch_bounds(256,2), 2 blocks/CU.
__global__ __launch_bounds__(256, 2)
void conv_main(const float* __restrict__ x, const unsigned short* __restrict__ bt,
               const float* __restrict__ bias, float* __restrict__ out)
{
  __shared__ __align__(16) char lds[4 * SLOT];   // 64 KB (A staging; epi reuses)

  const int tid  = threadIdx.x;
  const int lane = tid & 63;
  const int l15  = lane & 15;
  const int l4   = lane >> 4;
  const int wid  = tid >> 6;
  const int wm   = wid >> 1;    // 2: w-half
  const int wn   = wid & 1;     // 2: F-half of this fi half (64 cols)

  // XCD-aware bijective swizzle: nwg=2048, 256 per XCD.
  int bid  = (int)blockIdx.x;
  int work = (bid & 7) * 256 + (bid >> 3);
  int fi  = work & 1;
  int mi2 = work >> 1;          // 0..1023 : (b, h-pair)
  int bb  = mi2 >> 6;
  int h0  = (mi2 & 63) * 2;
  int F0  = fi * 128;

  const char* bimg = (const char*)bt + (size_t)fi * 9 * 16384;
  const int boff = (wn * 4) * 2048 + lane * 16;

  bf16x8 breg[2][4][2];   // double buffer = 64 VGPR, all-static indices

  // ---- prologue: B(0) -> buf0 (issues first, flies under staging VALU) ----
  #pragma unroll
  for (int n = 0; n < 4; ++n)
    #pragma unroll
    for (int kk = 0; kk < 2; ++kk)
      breg[0][n][kk] = *(const bf16x8*)(bimg + boff + n * 2048 + kk * 1024);

  // ---- stage A rows h0-1..h0+2 -> slots 0..3 (cast in-kernel) ----
  #pragma unroll
  for (int i = 0; i < 16; ++i) {
    int idx = tid + i * 256;            // 4096 16B-blocks (4 rows)
    int cb = idx & 7;
    int w  = (idx >> 3) & 127;
    int r  = idx >> 10;                 // 0..3
    int xr = (h0 + r + 127) & 127;      // row h0-1+r
    const float* src = x + (((size_t)(bb * NH + xr) * NW + w) * NC + cb * 8);
    float4 a0 = *(const float4*)(src);
    float4 a1 = *(const float4*)(src + 4);
    union { unsigned short u[8]; i32x4 v; } p;
    p.u[0] = f2b(a0.x); p.u[1] = f2b(a0.y); p.u[2] = f2b(a0.z); p.u[3] = f2b(a0.w);
    p.u[4] = f2b(a1.x); p.u[5] = f2b(a1.y); p.u[6] = f2b(a1.z); p.u[7] = f2b(a1.w);
    *(i32x4*)(lds + (r * SLOT + w * 128 + ((cb ^ (w & 7)) << 4))) = p.v;
  }
  __syncthreads();    // A staged; read-only hereafter

  // compressed A-address LUT (R10-verified), shared by both rows:
  //   addr(m,dwi) = slotb + ((trow[dwi] + m*2048) & 16383) + swz[dwi]
  //   kk=1 address = kk=0 address XOR 64
  int trow[3], swz[3];
  #pragma unroll
  for (int dwi = 0; dwi < 3; ++dwi) {
    int t = l15 + 1 - dwi;
    trow[dwi] = ((wm * 64 + t) & 127) * 128;
    swz[dwi]  = (l4 ^ (t & 7)) << 4;
  }

  f32x4 acc[2][4][4];   // [row][m][n], swapped layout — 128 VGPR
  #pragma unroll
  for (int rr = 0; rr < 2; ++rr)
    #pragma unroll
    for (int m = 0; m < 4; ++m)
      #pragma unroll
      for (int n = 0; n < 4; ++n)
        acc[rr][m][n] = (f32x4){0.f, 0.f, 0.f, 0.f};

  #pragma unroll
  for (int s = 0; s < 9; ++s) {
    if (s < 8) {  // depth-1 B prefetch -> other buffer (plain cached loads)
      const char* bs = bimg + (size_t)(s + 1) * 16384 + boff;
      #pragma unroll
      for (int n = 0; n < 4; ++n)
        #pragma unroll
        for (int kk = 0; kk < 2; ++kk)
          breg[(s + 1) & 1][n][kk] = *(const bf16x8*)(bs + n * 2048 + kk * 1024);
    }
    const int dwi = s / 3;                          // static
    // out row h0+rr reads x row h0+rr+1-(s%3) = slot (rr + 2 - s%3)
    #pragma unroll
    for (int kk = 0; kk < 2; ++kk) {
      #pragma unroll
      for (int rr = 0; rr < 2; ++rr) {
        const int slotb = (rr + 2 - (s % 3)) * SLOT;   // static, 0..3
        bf16x8 af[4];
        #pragma unroll
        for (int m = 0; m < 4; ++m) {
          int addr = slotb + ((trow[dwi] + m * 2048) & 16383) + swz[dwi];
          af[m] = *(const bf16x8*)(lds + (addr ^ (kk << 6)));
        }
        __builtin_amdgcn_s_setprio(1);
        #pragma unroll
        for (int m = 0; m < 4; ++m)
          #pragma unroll
          for (int n = 0; n < 4; ++n)
            acc[rr][m][n] = __builtin_amdgcn_mfma_f32_16x16x32_bf16(
                breg[s & 1][n][kk], af[m], acc[rr][m][n], 0, 0, 0);   // SWAPPED
        __builtin_amdgcn_s_setprio(0);
      }
    }
  }

  // ---- epilogue: f32x4 bias + b128 deposit + NT full-line stores,
  //      raw EPI_BARs only (R20-verified), per row x per chunk ----
  f32x4 bq[4];
  #pragma unroll
  for (int n = 0; n < 4; ++n)
    bq[n] = *(const f32x4*)(bias + F0 + wn * 64 + n * 16 + l4 * 4);

  EPI_BAR();                            // A ds_reads complete before eb overwrite
  float* eb = (float*)lds;              // [64][EBS=136] padded f32 tile (34.8 KB)

  #pragma unroll
  for (int rr = 0; rr < 2; ++rr) {
    #pragma unroll
    for (int chunk = 0; chunk < 2; ++chunk) {
      if (wm == chunk) {                // owning wave-pair deposits acc+bias
        #pragma unroll
        for (int m = 0; m < 4; ++m) {
          int r = m * 16 + l15;         // 0..63 chunk-local w row
          #pragma unroll
          for (int n = 0; n < 4; ++n) {
            int c = wn * 64 + n * 16 + l4 * 4;
            *(f32x4*)(eb + r * EBS + c) = acc[rr][m][n] + bq[n];  // ds_write_b128
          }
        }
      }
      EPI_BAR();                        // deposits visible (lgkmcnt only)
      size_t obase = ((size_t)(bb * NH + h0 + rr) * NW + chunk * 64) * NF + F0;
      #pragma unroll
      for (int i = 0; i < 8; ++i) {
        int r = i * 8 + wid * 2 + (lane >> 5);
        int c = (lane & 31) * 4;
        f32x4 v = *(const f32x4*)(eb + r * EBS + c);
        __builtin_nontemporal_store(v, (f32x4*)(out + obase + (size_t)r * NF + c));
      }
      if (rr != 1 || chunk != 1) EPI_BAR();   // eb reads done; stores keep flying
    }
  }
}

extern "C" void kernel_launch(void* const* d_in, const int* in_sizes, int n_in,
                              void* d_out, int out_size, void* d_ws, size_t ws_size,
                              hipStream_t stream) {
  const float* x    = (const float*)d_in[0];
  const float* kern = (const float*)d_in[1];
  const float* bias = (const float*)d_in[2];
  float* out = (float*)d_out;
  unsigned short* bt = (unsigned short*)d_ws;   // 294912 bytes

  prep_bt<<<dim3(72), dim3(256), 0, stream>>>(kern, bt);
  conv_main<<<dim3(2048), dim3(256), 0, stream>>>(x, bt, bias, out);
}